// Round 5
// baseline (41262.952 us; speedup 1.0000x reference)
//
#include <hip/hip_runtime.h>
#include <stdint.h>
#include <math.h>

namespace {

constexpr int B = 256, L = 256, F = 38, H = 512, D = 512, Z = 16, NF = 20;
constexpr float LOG2PI_F = 1.8378770664093453f;
constexpr int LBZ = L * B * Z;      // 1048576
constexpr int HALF = LBZ / 2;       // 524288
constexpr int HB = H * B;           // 131072
constexpr int DB = D * B;           // 131072
constexpr int ZB = Z * B;           // 4096
constexpr int LFB = L * F * B;      // 2490368
constexpr int GRIDN = 512;          // persistent grid: 2 blocks/CU on 256 CUs

// ---------------- coherent activation access (cross-XCD via L3) ------------
// Agent-scope relaxed atomics compile to sc1 loads/stores: stores write
// through to the die-level L3, loads read it, bypassing the (non-coherent)
// per-XCD L2. Weights use plain cached loads and stay L2-resident.
__device__ __forceinline__ float aload_(const float* p) {
  return __hip_atomic_load(p, __ATOMIC_RELAXED, __HIP_MEMORY_SCOPE_AGENT);
}
__device__ __forceinline__ void astore_(float* p, float v) {
  __hip_atomic_store(p, v, __ATOMIC_RELAXED, __HIP_MEMORY_SCOPE_AGENT);
}

// ---------------- math helpers ----------------

__device__ __forceinline__ float sigmoidf_(float x) {
  return 1.0f / (1.0f + expf(-x));
}
__device__ __forceinline__ float softplusf_(float x) {
  return fmaxf(x, 0.0f) + log1pf(expf(-fabsf(x)));
}

__device__ __forceinline__ void waveReduceAtomicAdd(float* dst, float v, int tid) {
  #pragma unroll
  for (int off = 32; off > 0; off >>= 1) v += __shfl_down(v, off, 64);
  if ((tid & 63) == 0) atomicAdd(dst, v);
}

// ---------------- 3-level grid barrier (monotone, no resets) ---------------
// Proven correct in R4. 512 blocks: 64 L1 groups of 8 -> 8 L2 groups -> root.
__device__ __forceinline__ void gsync_(uint32_t* bar, int blk, uint32_t n) {
  __syncthreads();
  if (threadIdx.x == 0) {
    const uint32_t tgt = 8u * n - 1u;
    uint32_t o1 = __hip_atomic_fetch_add(&bar[192 + ((blk >> 3) << 4)], 1u,
                                         __ATOMIC_RELEASE, __HIP_MEMORY_SCOPE_AGENT);
    if (o1 == tgt) {
      uint32_t o2 = __hip_atomic_fetch_add(&bar[32 + ((blk >> 6) << 4)], 1u,
                                           __ATOMIC_RELEASE, __HIP_MEMORY_SCOPE_AGENT);
      if (o2 == tgt) {
        uint32_t o3 = __hip_atomic_fetch_add(&bar[16], 1u,
                                             __ATOMIC_RELEASE, __HIP_MEMORY_SCOPE_AGENT);
        if (o3 == tgt)
          __hip_atomic_store(&bar[0], n, __ATOMIC_RELEASE, __HIP_MEMORY_SCOPE_AGENT);
      }
    }
    while (__hip_atomic_load(&bar[0], __ATOMIC_RELAXED, __HIP_MEMORY_SCOPE_AGENT) < n)
      __builtin_amdgcn_s_sleep(1);
  }
  __syncthreads();
}

// ---------------- threefry2x32 (JAX-compatible) ----------------

__host__ __device__ inline uint32_t rotl32_(uint32_t x, int d) {
  return (x << d) | (x >> (32 - d));
}

__host__ __device__ inline void threefry2x32_(uint32_t k0, uint32_t k1,
                                              uint32_t x0, uint32_t x1,
                                              uint32_t& o0, uint32_t& o1) {
  const uint32_t ks2 = k0 ^ k1 ^ 0x1BD11BDAu;
  uint32_t v0 = x0 + k0;
  uint32_t v1 = x1 + k1;
#define TF_RND(r) { v0 += v1; v1 = rotl32_(v1, r); v1 ^= v0; }
  TF_RND(13) TF_RND(15) TF_RND(26) TF_RND(6)
  v0 += k1;  v1 += ks2 + 1u;
  TF_RND(17) TF_RND(29) TF_RND(16) TF_RND(24)
  v0 += ks2; v1 += k0 + 2u;
  TF_RND(13) TF_RND(15) TF_RND(26) TF_RND(6)
  v0 += k0;  v1 += k1 + 3u;
  TF_RND(17) TF_RND(29) TF_RND(16) TF_RND(24)
  v0 += k1;  v1 += ks2 + 4u;
  TF_RND(13) TF_RND(15) TF_RND(26) TF_RND(6)
  v0 += ks2; v1 += k0 + 5u;
#undef TF_RND
  o0 = v0; o1 = v1;
}

__device__ __forceinline__ float erfinv_f_(float x) {
  float w = -log1pf(-x * x);
  float p;
  if (w < 5.0f) {
    w -= 2.5f;
    p = 2.81022636e-08f;
    p = fmaf(p, w, 3.43273939e-07f);
    p = fmaf(p, w, -3.5233877e-06f);
    p = fmaf(p, w, -4.39150654e-06f);
    p = fmaf(p, w, 0.00021858087f);
    p = fmaf(p, w, -0.00125372503f);
    p = fmaf(p, w, -0.00417768164f);
    p = fmaf(p, w, 0.246640727f);
    p = fmaf(p, w, 1.50140941f);
  } else {
    w = sqrtf(w) - 3.0f;
    p = -0.000200214257f;
    p = fmaf(p, w, 0.000100950558f);
    p = fmaf(p, w, 0.00134934322f);
    p = fmaf(p, w, -0.00367342844f);
    p = fmaf(p, w, 0.00573950773f);
    p = fmaf(p, w, -0.0076224613f);
    p = fmaf(p, w, 0.00943887047f);
    p = fmaf(p, w, 1.00167406f);
    p = fmaf(p, w, 2.83297682f);
  }
  return p * x;
}

__device__ __forceinline__ float bits_to_normal_(uint32_t bits) {
  uint32_t m = (bits >> 9) | 0x3f800000u;
  float f = __uint_as_float(m) - 1.0f;
  float u = f * 2.0f + (-0.99999994f);
  u = fmaxf(-0.99999994f, u);
  return 1.41421356f * erfinv_f_(u);
}

// planar flows for one batch column (per-lane), returns logdet; zv updated in place
__device__ __forceinline__ float flows_dev(float zv[Z], const float* __restrict__ pu,
                                           const float* __restrict__ pw,
                                           const float* __restrict__ pb) {
  float ld = 0.0f;
  for (int f = 0; f < NF; ++f) {
    const float* w = pw + f * Z;
    const float* u = pu + f * Z;
    float wn2 = 0.0f, wu = 0.0f;
    #pragma unroll
    for (int i = 0; i < Z; ++i) { wn2 = fmaf(w[i], w[i], wn2); wu = fmaf(w[i], u[i], wu); }
    float coef = (softplusf_(wu) - 1.0f - wu) / wn2;
    float a_in = pb[f];
    #pragma unroll
    for (int i = 0; i < Z; ++i) a_in = fmaf(zv[i], w[i], a_in);
    float a = tanhf(a_in);
    float uw = 0.0f;
    #pragma unroll
    for (int i = 0; i < Z; ++i) {
      float uh = fmaf(coef, w[i], u[i]);
      uw = fmaf(uh, w[i], uw);
      zv[i] = fmaf(uh, a, zv[i]);
    }
    ld += logf(fabsf(1.0f + (1.0f - a * a) * uw) + 1e-12f);
  }
  return ld;
}

// ---------------- small utility kernels ----------------

__global__ __launch_bounds__(256) void k_transpose_x(const float* __restrict__ x,
                                                     float* __restrict__ xT) {
  int idx = blockIdx.x * blockDim.x + threadIdx.x;  // over B*L*F
  int f = idx % F;
  int t = (idx / F) % L;
  int b = idx / (F * L);
  xT[(t * F + f) * B + b] = x[idx];
}

__global__ __launch_bounds__(256) void k_noise(float* __restrict__ eps_z,
                                               float* __restrict__ kld_acc,
                                               uint32_t kz0, uint32_t kz1,
                                               uint32_t kp0, uint32_t kp1) {
  int i = blockIdx.x * blockDim.x + threadIdx.x;  // [0, HALF)
  uint32_t a0, a1, b0, b1;
  threefry2x32_(kz0, kz1, (uint32_t)i, (uint32_t)(i + HALF), a0, a1);
  float ez0 = bits_to_normal_(a0);
  float ez1 = bits_to_normal_(a1);
  eps_z[i] = ez0;
  eps_z[i + HALF] = ez1;
  threefry2x32_(kp0, kp1, (uint32_t)i, (uint32_t)(i + HALF), b0, b1);
  float ep0 = bits_to_normal_(b0);
  float ep1 = bits_to_normal_(b1);
  float local = -0.5f * (ez0 * ez0 + ez1 * ez1) + 0.5f * (ep0 * ep0 + ep1 * ep1);
  waveReduceAtomicAdd(kld_acc, local, threadIdx.x);
}

__global__ void k_finalize(const float* __restrict__ acc, float* __restrict__ out) {
  out[(size_t)B * L * F] = acc[1];      // recon
  out[(size_t)B * L * F + 1] = acc[0];  // kld
}

// ---------------- weight composition (once per launch) ----------------
__global__ __launch_bounds__(256) void k_compose(
    const float* __restrict__ A, const float* __restrict__ bA,
    const float* __restrict__ W2, const float* __restrict__ b2,
    float* __restrict__ Wc, float* __restrict__ bc) {
  const int r = blockIdx.x;
  const int k = threadIdx.x;
  float acc0 = 0.f, acc1 = 0.f;
  for (int j = 0; j < D; ++j) {
    float a = A[(size_t)r * D + j];          // wave-uniform
    acc0 = fmaf(a, W2[(size_t)j * D + k], acc0);
    acc1 = fmaf(a, W2[(size_t)j * D + k + 256], acc1);
  }
  Wc[(size_t)r * D + k] = acc0;
  Wc[(size_t)r * D + k + 256] = acc1;
  float accb = 0.f;
  for (int j = k; j < D; j += 256) accb += A[(size_t)r * D + j] * b2[j];
  __shared__ float s[256];
  s[k] = accb;
  __syncthreads();
  for (int off = 128; off > 0; off >>= 1) {
    if (k < off) s[k] += s[k + off];
    __syncthreads();
  }
  if (k == 0) bc[r] = s[0] + bA[r];
}

// ---------------- staged-chunk helpers ----------------
// Stage a 64-row chunk of src[k][b] (rows kbase..kbase+63, cols b0..b0+63)
// into LDS buf[64][64] via 16 pipelined sc1 loads per thread. Load issues
// early (returns values in sv); write happens late (after compute).
__device__ __forceinline__ void stage_load_(float sv[16], const float* src,
                                            int kbase, int b) {
  const float* p = src + (size_t)kbase * B + b;
  #pragma unroll
  for (int m = 0; m < 16; ++m) sv[m] = aload_(p + (size_t)m * B);
}
__device__ __forceinline__ void stage_write_(const float sv[16], float* buf,
                                             int wv, int lane) {
  float* bw = buf + wv * 16 * 64 + lane;
  #pragma unroll
  for (int m = 0; m < 16; ++m) bw[m * 64] = sv[m];
}

// ---------------- GRU phase (16 rows/block, row-split: 4 rows/wave) --------
// blk2 in [0,128): rb=blk2>>2 (j0=rb*16), bg=blk2&3 (b0=bg*64).
// THETA: every wave computes flows(z0) redundantly for its lanes (z-part);
// (rb==0, wv==0) publishes -logdet once per column.
template<bool THETA>
__device__ __forceinline__ void gru_phase(
    int blk2, const float* __restrict__ xin, const float* __restrict__ hT,
    const float* __restrict__ Wih, const float* __restrict__ Whh,
    const float* __restrict__ bih, const float* __restrict__ bhh,
    float* __restrict__ hout,
    const float* pu, const float* pw, const float* pb, float* kld_acc,
    float* lds) {
  const int lane = threadIdx.x & 63;
  const int wv = __builtin_amdgcn_readfirstlane(threadIdx.x >> 6);
  const int rb = blk2 >> 2;
  const int j0 = rb * 16;
  const int b0 = (blk2 & 3) * 64;
  const int b = b0 + lane;
  const int jr0 = j0 + wv * 4;

  float aR[4], aZ[4], aNX[4], aNH[4];
  #pragma unroll
  for (int r = 0; r < 4; ++r) { aR[r] = 0.f; aZ[r] = 0.f; aNX[r] = 0.f; aNH[r] = 0.f; }

  float* buf0 = lds;
  float* buf1 = lds + 64 * 64;

  float sv[16];
  stage_load_(sv, hT, wv * 16, b);   // chunk 0 in flight

  // x/z part (overlaps chunk-0 load latency)
  if (THETA) {
    float zv[Z];
    #pragma unroll
    for (int zk = 0; zk < Z; ++zk) zv[zk] = aload_(xin + zk * B + b);
    float ld = flows_dev(zv, pu, pw, pb);
    #pragma unroll
    for (int zk = 0; zk < Z; zk += 4) {
      #pragma unroll
      for (int r = 0; r < 4; ++r) {
        const float4 w0 = *(const float4*)(Wih + (size_t)(0 * H + jr0 + r) * Z + zk);
        const float4 w1 = *(const float4*)(Wih + (size_t)(1 * H + jr0 + r) * Z + zk);
        const float4 w2 = *(const float4*)(Wih + (size_t)(2 * H + jr0 + r) * Z + zk);
        aR[r]  = fmaf(w0.x, zv[zk], fmaf(w0.y, zv[zk+1], fmaf(w0.z, zv[zk+2], fmaf(w0.w, zv[zk+3], aR[r]))));
        aZ[r]  = fmaf(w1.x, zv[zk], fmaf(w1.y, zv[zk+1], fmaf(w1.z, zv[zk+2], fmaf(w1.w, zv[zk+3], aZ[r]))));
        aNX[r] = fmaf(w2.x, zv[zk], fmaf(w2.y, zv[zk+1], fmaf(w2.z, zv[zk+2], fmaf(w2.w, zv[zk+3], aNX[r]))));
      }
    }
    if (wv == 0 && rb == 0) waveReduceAtomicAdd(kld_acc, -ld, lane);
  } else {
    #pragma unroll 2
    for (int k = 0; k < F; ++k) {
      const float a = xin[k * B + b];   // plain cached (input tensor)
      #pragma unroll
      for (int r = 0; r < 4; ++r) {
        aR[r]  = fmaf(Wih[(size_t)(0 * H + jr0 + r) * F + k], a, aR[r]);
        aZ[r]  = fmaf(Wih[(size_t)(1 * H + jr0 + r) * F + k], a, aZ[r]);
        aNX[r] = fmaf(Wih[(size_t)(2 * H + jr0 + r) * F + k], a, aNX[r]);
      }
    }
  }

  stage_write_(sv, buf0, wv, lane);
  __syncthreads();

  for (int c = 0; c < 8; ++c) {
    float* cur = (c & 1) ? buf1 : buf0;
    float* nxt = (c & 1) ? buf0 : buf1;
    if (c < 7) stage_load_(sv, hT, (c + 1) * 64 + wv * 16, b);
    const int kb = c * 64;
    #pragma unroll 4
    for (int kl = 0; kl < 64; kl += 4) {
      const float a0 = cur[(kl + 0) * 64 + lane];
      const float a1 = cur[(kl + 1) * 64 + lane];
      const float a2 = cur[(kl + 2) * 64 + lane];
      const float a3 = cur[(kl + 3) * 64 + lane];
      const int k = kb + kl;
      #pragma unroll
      for (int r = 0; r < 4; ++r) {
        const float4 w0 = *(const float4*)(Whh + (size_t)(0 * H + jr0 + r) * H + k);
        const float4 w1 = *(const float4*)(Whh + (size_t)(1 * H + jr0 + r) * H + k);
        const float4 w2 = *(const float4*)(Whh + (size_t)(2 * H + jr0 + r) * H + k);
        aR[r]  = fmaf(w0.x, a0, fmaf(w0.y, a1, fmaf(w0.z, a2, fmaf(w0.w, a3, aR[r]))));
        aZ[r]  = fmaf(w1.x, a0, fmaf(w1.y, a1, fmaf(w1.z, a2, fmaf(w1.w, a3, aZ[r]))));
        aNH[r] = fmaf(w2.x, a0, fmaf(w2.y, a1, fmaf(w2.z, a2, fmaf(w2.w, a3, aNH[r]))));
      }
    }
    if (c < 7) stage_write_(sv, nxt, wv, lane);
    __syncthreads();
  }

  #pragma unroll
  for (int r = 0; r < 4; ++r) {
    const int j = jr0 + r;
    const float rg = sigmoidf_(aR[r] + bih[j] + bhh[j]);
    const float zg = sigmoidf_(aZ[r] + bih[H + j] + bhh[H + j]);
    const float ng = tanhf(aNX[r] + bih[2 * H + j] + rg * (aNH[r] + bhh[2 * H + j]));
    const float hp = aload_(hT + (size_t)j * B + b);
    astore_(hout + (size_t)j * B + b, (1.0f - zg) * ng + zg * hp);
  }
}

// ---------------- MLP1 phase (16 rows/block, 4 rows/wave) ------------------
// PHI: Kv=528, z-part via per-wave redundant flows(z0prev); else Kv=512.
template<bool PHI>
__device__ __forceinline__ void mlp1_phase(
    int blk2, const float* __restrict__ hin, const float* __restrict__ z0prev,
    const float* __restrict__ W, const float* __restrict__ bias,
    float* __restrict__ outT,
    const float* pu, const float* pw, const float* pb, float* lds) {
  const int lane = threadIdx.x & 63;
  const int wv = __builtin_amdgcn_readfirstlane(threadIdx.x >> 6);
  const int r0 = (blk2 >> 2) * 16;
  const int b0 = (blk2 & 3) * 64;
  const int b = b0 + lane;
  const int jr0 = r0 + wv * 4;
  constexpr int Kv = PHI ? (H + Z) : H;

  float acc[4] = {0.f, 0.f, 0.f, 0.f};
  float* buf0 = lds;
  float* buf1 = lds + 64 * 64;

  float sv[16];
  stage_load_(sv, hin, wv * 16, b);

  if (PHI && z0prev != nullptr) {
    float zv[Z];
    #pragma unroll
    for (int zk = 0; zk < Z; ++zk) zv[zk] = aload_(z0prev + zk * B + b);
    flows_dev(zv, pu, pw, pb);
    #pragma unroll
    for (int zk = 0; zk < Z; zk += 4) {
      #pragma unroll
      for (int r = 0; r < 4; ++r) {
        const float4 w4 = *(const float4*)(W + (size_t)(jr0 + r) * Kv + H + zk);
        acc[r] = fmaf(w4.x, zv[zk], fmaf(w4.y, zv[zk+1], fmaf(w4.z, zv[zk+2], fmaf(w4.w, zv[zk+3], acc[r]))));
      }
    }
  }

  stage_write_(sv, buf0, wv, lane);
  __syncthreads();

  for (int c = 0; c < 8; ++c) {
    float* cur = (c & 1) ? buf1 : buf0;
    float* nxt = (c & 1) ? buf0 : buf1;
    if (c < 7) stage_load_(sv, hin, (c + 1) * 64 + wv * 16, b);
    const int kb = c * 64;
    #pragma unroll 4
    for (int kl = 0; kl < 64; kl += 4) {
      const float a0 = cur[(kl + 0) * 64 + lane];
      const float a1 = cur[(kl + 1) * 64 + lane];
      const float a2 = cur[(kl + 2) * 64 + lane];
      const float a3 = cur[(kl + 3) * 64 + lane];
      const int k = kb + kl;
      #pragma unroll
      for (int r = 0; r < 4; ++r) {
        const float4 w4 = *(const float4*)(W + (size_t)(jr0 + r) * Kv + k);
        acc[r] = fmaf(w4.x, a0, fmaf(w4.y, a1, fmaf(w4.z, a2, fmaf(w4.w, a3, acc[r]))));
      }
    }
    if (c < 7) stage_write_(sv, nxt, wv, lane);
    __syncthreads();
  }

  #pragma unroll
  for (int r = 0; r < 4; ++r) {
    const float s = fmaxf(acc[r] + bias[jr0 + r], 0.f);
    astore_(outT + (size_t)(jr0 + r) * B + b, s);
  }
}

// ---------------- z head phase: blk2 in [0,8): 8 z/block, 2 z/wave ---------
__device__ __forceinline__ void zhead_phase(
    int blk2, const float* __restrict__ h1T,
    const float* __restrict__ Wzl, const float* __restrict__ bzl,
    const float* __restrict__ Wzs, const float* __restrict__ bzs,
    const float* __restrict__ eps_t, float* __restrict__ z0T,
    float* kld_acc, float* lds) {
  const int lane = threadIdx.x & 63;
  const int wv = __builtin_amdgcn_readfirstlane(threadIdx.x >> 6);
  const int zz0 = (blk2 >> 2) * 8 + wv * 2;
  const int b0 = (blk2 & 3) * 64;
  const int b = b0 + lane;

  const float* wr[4] = {Wzl + (size_t)zz0 * D, Wzs + (size_t)zz0 * D,
                        Wzl + (size_t)(zz0 + 1) * D, Wzs + (size_t)(zz0 + 1) * D};
  float acc[4] = {0.f, 0.f, 0.f, 0.f};
  float* buf0 = lds;
  float* buf1 = lds + 64 * 64;

  float sv[16];
  stage_load_(sv, h1T, wv * 16, b);
  stage_write_(sv, buf0, wv, lane);
  __syncthreads();

  for (int c = 0; c < 8; ++c) {
    float* cur = (c & 1) ? buf1 : buf0;
    float* nxt = (c & 1) ? buf0 : buf1;
    if (c < 7) stage_load_(sv, h1T, (c + 1) * 64 + wv * 16, b);
    const int kb = c * 64;
    #pragma unroll 4
    for (int kl = 0; kl < 64; kl += 4) {
      const float a0 = cur[(kl + 0) * 64 + lane];
      const float a1 = cur[(kl + 1) * 64 + lane];
      const float a2 = cur[(kl + 2) * 64 + lane];
      const float a3 = cur[(kl + 3) * 64 + lane];
      const int k = kb + kl;
      #pragma unroll
      for (int q = 0; q < 4; ++q) {
        const float4 w4 = *(const float4*)(wr[q] + k);
        acc[q] = fmaf(w4.x, a0, fmaf(w4.y, a1, fmaf(w4.z, a2, fmaf(w4.w, a3, acc[q]))));
      }
    }
    if (c < 7) stage_write_(sv, nxt, wv, lane);
    __syncthreads();
  }

  float kacc = 0.f;
  #pragma unroll
  for (int t = 0; t < 2; ++t) {
    const int zz = zz0 + t;
    const float sl = acc[2 * t] + bzl[zz];
    const float ss = acc[2 * t + 1] + bzs[zz];
    const float scale = softplusf_(ss) + 1e-6f;
    const float ez = eps_t[b * Z + zz];
    astore_(z0T + zz * B + b, sl + scale * ez);
    kacc -= logf(scale);
  }
  waveReduceAtomicAdd(kld_acc, kacc, lane);
}

// ---------------- y head phase: blk2 in [0,20): 8 f/block, 2 f/wave --------
__device__ __forceinline__ void yhead_phase(
    int blk2, int t, const float* __restrict__ g1T,
    const float* __restrict__ Wyl, const float* __restrict__ byl,
    const float* __restrict__ Wys, const float* __restrict__ bys,
    const float* __restrict__ xT, float* __restrict__ out_yloc,
    float* recon_acc, float* lds) {
  const int lane = threadIdx.x & 63;
  const int wv = __builtin_amdgcn_readfirstlane(threadIdx.x >> 6);
  const int ff0 = (blk2 >> 2) * 8 + wv * 2;
  const int b0 = (blk2 & 3) * 64;
  const int b = b0 + lane;
  const int fc0 = (ff0 < F) ? ff0 : 0;
  const int fc1 = (ff0 + 1 < F) ? (ff0 + 1) : 0;

  const float* wr[4] = {Wyl + (size_t)fc0 * D, Wys + (size_t)fc0 * D,
                        Wyl + (size_t)fc1 * D, Wys + (size_t)fc1 * D};
  float acc[4] = {0.f, 0.f, 0.f, 0.f};
  float* buf0 = lds;
  float* buf1 = lds + 64 * 64;

  float sv[16];
  stage_load_(sv, g1T, wv * 16, b);
  stage_write_(sv, buf0, wv, lane);
  __syncthreads();

  for (int c = 0; c < 8; ++c) {
    float* cur = (c & 1) ? buf1 : buf0;
    float* nxt = (c & 1) ? buf0 : buf1;
    if (c < 7) stage_load_(sv, g1T, (c + 1) * 64 + wv * 16, b);
    const int kb = c * 64;
    #pragma unroll 4
    for (int kl = 0; kl < 64; kl += 4) {
      const float a0 = cur[(kl + 0) * 64 + lane];
      const float a1 = cur[(kl + 1) * 64 + lane];
      const float a2 = cur[(kl + 2) * 64 + lane];
      const float a3 = cur[(kl + 3) * 64 + lane];
      const int k = kb + kl;
      #pragma unroll
      for (int q = 0; q < 4; ++q) {
        const float4 w4 = *(const float4*)(wr[q] + k);
        acc[q] = fmaf(w4.x, a0, fmaf(w4.y, a1, fmaf(w4.z, a2, fmaf(w4.w, a3, acc[q]))));
      }
    }
    if (c < 7) stage_write_(sv, nxt, wv, lane);
    __syncthreads();
  }

  float nl = 0.f;
  #pragma unroll
  for (int q = 0; q < 2; ++q) {
    const int ff = ff0 + q;
    if (ff < F) {
      const float loc = acc[2 * q] + byl[ff];
      const float sp = acc[2 * q + 1] + bys[ff];
      const float scale = softplusf_(sp) + 1e-6f;
      out_yloc[((size_t)b * L + t) * F + ff] = loc;
      const float xv = xT[((size_t)t * F + ff) * B + b];
      const float d = (xv - loc) / scale;
      nl += 0.5f * d * d + logf(scale) + 0.5f * LOG2PI_F;
    }
  }
  waveReduceAtomicAdd(recon_acc, nl, lane);
}

// ---------------- persistent kernel ----------------
struct PP {
  const float *xT, *eps_z;
  const float *phi_Wih, *phi_Whh, *phi_bih, *phi_bhh, *phi_W1, *phi_b1;
  const float *th_Wih, *th_Whh, *th_bih, *th_bhh, *th_W1, *th_b1;
  const float *Wzl, *bzl, *Wzs, *bzs, *Wyl, *byl, *Wys, *bys;
  const float *pu, *pw, *pb;
  float *phi0, *phi1, *th0, *th1, *z0a, *z0b, *h1T, *g1T, *acc, *out;
  uint32_t* bar;
};

// Schedule (R4 skew), 2 grid barriers per iteration:
//   A(i): phiGRU(i)[0..127] | thGRU(i-2)[128..255] | zhead(i-1)[256..263]
//         | yhead(i-3)[264..283]
//   B(i): phiMLP1(i)+flows[0..127] | thMLP1(i-2)[128..255]
__global__ __launch_bounds__(256, 2) void k_persist(PP P) {
  __shared__ float lds[2 * 64 * 64];   // 32 KB double-buffered staging
  const int blk = blockIdx.x;
  uint32_t n = 0;

  for (int i = 0; i <= L + 2; ++i) {
    const bool hasPhi = (i < L);
    const bool hasTh  = (i >= 2 && i <= L + 1);
    const bool hasZ   = (i >= 1 && i <= L);
    const bool hasY   = (i >= 3);

    const float* xt     = P.xT + (size_t)(hasPhi ? i : 0) * F * B;
    const float* phi_c  = (i & 1) ? P.phi1 : P.phi0;   // phi_h(i-1)
    float*       phi_n  = (i & 1) ? P.phi0 : P.phi1;   // phi_h(i)
    const float* z0_in  = (i & 1) ? P.z0b : P.z0a;     // z0(i-2)
    const float* th_c   = (i & 1) ? P.th0 : P.th1;     // th_h(i-3)
    float*       th_n   = (i & 1) ? P.th1 : P.th0;     // th_h(i-2)
    float*       z0_out = (i & 1) ? P.z0a : P.z0b;     // z0(i-1)

    // ---- phase A ----
    if (blk < 128) {
      if (hasPhi)
        gru_phase<false>(blk, xt, phi_c, P.phi_Wih, P.phi_Whh, P.phi_bih,
                         P.phi_bhh, phi_n, nullptr, nullptr, nullptr, nullptr,
                         lds);
    } else if (blk < 256) {
      if (hasTh)
        gru_phase<true>(blk - 128, z0_in, th_c, P.th_Wih, P.th_Whh, P.th_bih,
                        P.th_bhh, th_n, P.pu, P.pw, P.pb, P.acc, lds);
    } else if (blk < 264) {
      if (hasZ)
        zhead_phase(blk - 256, P.h1T, P.Wzl, P.bzl, P.Wzs, P.bzs,
                    P.eps_z + (size_t)(i - 1) * B * Z, z0_out, P.acc, lds);
    } else if (blk < 284) {
      if (hasY)
        yhead_phase(blk - 264, i - 3, P.g1T, P.Wyl, P.byl, P.Wys, P.bys,
                    P.xT, P.out, P.acc + 1, lds);
    }
    ++n; gsync_(P.bar, blk, n);

    // ---- phase B ----
    if (blk < 128) {
      if (hasPhi)
        mlp1_phase<true>(blk, phi_n, (i >= 1) ? z0_out : nullptr,
                         P.phi_W1, P.phi_b1, P.h1T, P.pu, P.pw, P.pb, lds);
    } else if (blk < 256) {
      if (hasTh)
        mlp1_phase<false>(blk - 128, th_n, nullptr,
                          P.th_W1, P.th_b1, P.g1T, P.pu, P.pw, P.pb, lds);
    }
    ++n; gsync_(P.bar, blk, n);
  }
}

}  // namespace

extern "C" void kernel_launch(void* const* d_in, const int* in_sizes, int n_in,
                              void* d_out, int out_size, void* d_ws, size_t ws_size,
                              hipStream_t stream) {
  const float* x        = (const float*)d_in[0];
  const float* phi_Wih  = (const float*)d_in[1];
  const float* phi_Whh  = (const float*)d_in[2];
  const float* phi_bih  = (const float*)d_in[3];
  const float* phi_bhh  = (const float*)d_in[4];
  const float* phi_W1   = (const float*)d_in[5];
  const float* phi_b1   = (const float*)d_in[6];
  const float* phi_W2   = (const float*)d_in[7];
  const float* phi_b2   = (const float*)d_in[8];
  const float* zloc_W   = (const float*)d_in[9];
  const float* zloc_b   = (const float*)d_in[10];
  const float* zscale_W = (const float*)d_in[11];
  const float* zscale_b = (const float*)d_in[12];
  const float* pu       = (const float*)d_in[13];
  const float* pw       = (const float*)d_in[14];
  const float* pb       = (const float*)d_in[15];
  const float* th_Wih   = (const float*)d_in[16];
  const float* th_Whh   = (const float*)d_in[17];
  const float* th_bih   = (const float*)d_in[18];
  const float* th_bhh   = (const float*)d_in[19];
  const float* th_W1    = (const float*)d_in[20];
  const float* th_b1    = (const float*)d_in[21];
  const float* th_W2    = (const float*)d_in[22];
  const float* th_b2    = (const float*)d_in[23];
  const float* xloc_W   = (const float*)d_in[24];
  const float* xloc_b   = (const float*)d_in[25];
  const float* xscale_W = (const float*)d_in[26];
  const float* xscale_b = (const float*)d_in[27];

  float* out = (float*)d_out;
  float* ws = (float*)d_ws;

  // workspace layout (floats)
  float* acc   = ws;                        // [0]=kld, [1]=recon
  uint32_t* bar = (uint32_t*)(ws + 64);     // 2048 dwords, cacheline-spread
  float* eps_z = ws + 64 + 2048;            // LBZ
  float* xT    = eps_z + LBZ;               // LFB
  float* phi0  = xT + LFB;                  // HB
  float* phi1  = phi0 + HB;                 // HB
  float* th0   = phi1 + HB;                 // HB
  float* th1   = th0 + HB;                  // HB
  float* z0a   = th1 + HB;                  // ZB
  float* z0b   = z0a + ZB;                  // ZB
  float* h1T   = z0b + ZB;                  // DB
  float* g1T   = h1T + DB;                  // DB
  float* Wzl   = g1T + DB;                  // Z*D
  float* Wzs   = Wzl + Z * D;               // Z*D
  float* bzl   = Wzs + Z * D;               // 64
  float* bzs   = bzl + 64;                  // 64
  float* Wyl   = bzs + 64;                  // F*D
  float* Wys   = Wyl + F * D;               // F*D
  float* byl   = Wys + F * D;               // 64
  float* bys   = byl + 64;                  // 64

  hipMemsetAsync(ws, 0, (64 + 2048) * sizeof(float), stream);   // acc + barrier
  hipMemsetAsync(phi0, 0, (size_t)HB * sizeof(float), stream);  // phi_h(-1)
  hipMemsetAsync(th1, 0, (size_t)HB * sizeof(float), stream);   // th_h(-1)

  // JAX PRNG: key(42)=(0,42); split -> kz, kp
  uint32_t a0, a1, b0, b1;
  threefry2x32_(0u, 42u, 0u, 2u, a0, a1);
  threefry2x32_(0u, 42u, 1u, 3u, b0, b1);
  const uint32_t kz0 = a0, kz1 = b0, kp0 = a1, kp1 = b1;

  k_transpose_x<<<(B * L * F) / 256, 256, 0, stream>>>(x, xT);
  k_noise<<<HALF / 256, 256, 0, stream>>>(eps_z, acc, kz0, kz1, kp0, kp1);

  // Compose linear MLP2 into the z/y heads: Wc = headW @ W2, bc = headW @ b2 + headb.
  k_compose<<<Z, 256, 0, stream>>>(zloc_W, zloc_b, phi_W2, phi_b2, Wzl, bzl);
  k_compose<<<Z, 256, 0, stream>>>(zscale_W, zscale_b, phi_W2, phi_b2, Wzs, bzs);
  k_compose<<<F, 256, 0, stream>>>(xloc_W, xloc_b, th_W2, th_b2, Wyl, byl);
  k_compose<<<F, 256, 0, stream>>>(xscale_W, xscale_b, th_W2, th_b2, Wys, bys);

  PP P;
  P.xT = xT; P.eps_z = eps_z;
  P.phi_Wih = phi_Wih; P.phi_Whh = phi_Whh; P.phi_bih = phi_bih; P.phi_bhh = phi_bhh;
  P.phi_W1 = phi_W1; P.phi_b1 = phi_b1;
  P.th_Wih = th_Wih; P.th_Whh = th_Whh; P.th_bih = th_bih; P.th_bhh = th_bhh;
  P.th_W1 = th_W1; P.th_b1 = th_b1;
  P.Wzl = Wzl; P.bzl = bzl; P.Wzs = Wzs; P.bzs = bzs;
  P.Wyl = Wyl; P.byl = byl; P.Wys = Wys; P.bys = bys;
  P.pu = pu; P.pw = pw; P.pb = pb;
  P.phi0 = phi0; P.phi1 = phi1; P.th0 = th0; P.th1 = th1;
  P.z0a = z0a; P.z0b = z0b; P.h1T = h1T; P.g1T = g1T;
  P.acc = acc; P.out = out; P.bar = bar;

  k_persist<<<GRIDN, 256, 0, stream>>>(P);

  k_finalize<<<1, 1, 0, stream>>>(acc, out);
}

// Round 6
// 32081.772 us; speedup vs baseline: 1.2862x; 1.2862x over previous
//
#include <hip/hip_runtime.h>
#include <stdint.h>
#include <math.h>

namespace {

constexpr int B = 256, L = 256, F = 38, H = 512, D = 512, Z = 16, NF = 20;
constexpr float LOG2PI_F = 1.8378770664093453f;
constexpr int LBZ = L * B * Z;      // 1048576
constexpr int HALF = LBZ / 2;       // 524288
constexpr int HB = H * B;           // 131072
constexpr int DB = D * B;           // 131072
constexpr int ZB = Z * B;           // 4096
constexpr int LFB = L * F * B;      // 2490368
constexpr int GRIDN = 512;          // persistent grid: 2 blocks/CU on 256 CUs

// ---------------- coherent activation access (cross-XCD via L3) ------------
// Agent-scope relaxed atomics compile to sc1 loads/stores: stores write
// through to the die-level L3, loads read it, bypassing the (non-coherent)
// per-XCD L2. Weights use plain cached loads and stay L2-resident.
__device__ __forceinline__ float aload_(const float* p) {
  return __hip_atomic_load(p, __ATOMIC_RELAXED, __HIP_MEMORY_SCOPE_AGENT);
}
__device__ __forceinline__ void astore_(float* p, float v) {
  __hip_atomic_store(p, v, __ATOMIC_RELAXED, __HIP_MEMORY_SCOPE_AGENT);
}

// ---------------- math helpers ----------------

__device__ __forceinline__ float sigmoidf_(float x) {
  return 1.0f / (1.0f + expf(-x));
}
__device__ __forceinline__ float softplusf_(float x) {
  return fmaxf(x, 0.0f) + log1pf(expf(-fabsf(x)));
}

__device__ __forceinline__ void waveReduceAtomicAdd(float* dst, float v, int tid) {
  #pragma unroll
  for (int off = 32; off > 0; off >>= 1) v += __shfl_down(v, off, 64);
  if ((tid & 63) == 0) atomicAdd(dst, v);
}

// ---------------- 3-level grid barrier (monotone, RELAXED-only) ------------
// KEY FIX vs R4: arrival RMWs are RELAXED, preceded by one explicit
// s_waitcnt vmcnt(0). RELEASE-ordered agent atomics on gfx950 force an L2
// writeback (buffer_wbl2) since per-XCD L2s are non-coherent — that was
// ~60us/barrier. Correctness is preserved because ALL cross-block data moves
// through sc1 (L2-bypassing) loads/stores: once vmcnt retires, the data is
// in L3 and visible; the barrier only orders control flow.
// Layout (uint32 idx): gen=bar[0]; root=bar[16]; L2[j]=bar[32+16j] (j<8);
// L1[j]=bar[192+16j] (j<64). Counters never reset (target 8n).
__device__ __forceinline__ void gsync_(uint32_t* bar, int blk, uint32_t n) {
  __syncthreads();
  if (threadIdx.x == 0) {
    asm volatile("s_waitcnt vmcnt(0)" ::: "memory");
    const uint32_t tgt = 8u * n - 1u;
    uint32_t o1 = __hip_atomic_fetch_add(&bar[192 + ((blk >> 3) << 4)], 1u,
                                         __ATOMIC_RELAXED, __HIP_MEMORY_SCOPE_AGENT);
    if (o1 == tgt) {
      uint32_t o2 = __hip_atomic_fetch_add(&bar[32 + ((blk >> 6) << 4)], 1u,
                                           __ATOMIC_RELAXED, __HIP_MEMORY_SCOPE_AGENT);
      if (o2 == tgt) {
        uint32_t o3 = __hip_atomic_fetch_add(&bar[16], 1u,
                                             __ATOMIC_RELAXED, __HIP_MEMORY_SCOPE_AGENT);
        if (o3 == tgt)
          __hip_atomic_store(&bar[0], n, __ATOMIC_RELAXED, __HIP_MEMORY_SCOPE_AGENT);
      }
    }
    while (__hip_atomic_load(&bar[0], __ATOMIC_RELAXED, __HIP_MEMORY_SCOPE_AGENT) < n)
      __builtin_amdgcn_s_sleep(1);
  }
  __syncthreads();
}

// ---------------- threefry2x32 (JAX-compatible) ----------------

__host__ __device__ inline uint32_t rotl32_(uint32_t x, int d) {
  return (x << d) | (x >> (32 - d));
}

__host__ __device__ inline void threefry2x32_(uint32_t k0, uint32_t k1,
                                              uint32_t x0, uint32_t x1,
                                              uint32_t& o0, uint32_t& o1) {
  const uint32_t ks2 = k0 ^ k1 ^ 0x1BD11BDAu;
  uint32_t v0 = x0 + k0;
  uint32_t v1 = x1 + k1;
#define TF_RND(r) { v0 += v1; v1 = rotl32_(v1, r); v1 ^= v0; }
  TF_RND(13) TF_RND(15) TF_RND(26) TF_RND(6)
  v0 += k1;  v1 += ks2 + 1u;
  TF_RND(17) TF_RND(29) TF_RND(16) TF_RND(24)
  v0 += ks2; v1 += k0 + 2u;
  TF_RND(13) TF_RND(15) TF_RND(26) TF_RND(6)
  v0 += k0;  v1 += k1 + 3u;
  TF_RND(17) TF_RND(29) TF_RND(16) TF_RND(24)
  v0 += k1;  v1 += ks2 + 4u;
  TF_RND(13) TF_RND(15) TF_RND(26) TF_RND(6)
  v0 += ks2; v1 += k0 + 5u;
#undef TF_RND
  o0 = v0; o1 = v1;
}

__device__ __forceinline__ float erfinv_f_(float x) {
  float w = -log1pf(-x * x);
  float p;
  if (w < 5.0f) {
    w -= 2.5f;
    p = 2.81022636e-08f;
    p = fmaf(p, w, 3.43273939e-07f);
    p = fmaf(p, w, -3.5233877e-06f);
    p = fmaf(p, w, -4.39150654e-06f);
    p = fmaf(p, w, 0.00021858087f);
    p = fmaf(p, w, -0.00125372503f);
    p = fmaf(p, w, -0.00417768164f);
    p = fmaf(p, w, 0.246640727f);
    p = fmaf(p, w, 1.50140941f);
  } else {
    w = sqrtf(w) - 3.0f;
    p = -0.000200214257f;
    p = fmaf(p, w, 0.000100950558f);
    p = fmaf(p, w, 0.00134934322f);
    p = fmaf(p, w, -0.00367342844f);
    p = fmaf(p, w, 0.00573950773f);
    p = fmaf(p, w, -0.0076224613f);
    p = fmaf(p, w, 0.00943887047f);
    p = fmaf(p, w, 1.00167406f);
    p = fmaf(p, w, 2.83297682f);
  }
  return p * x;
}

__device__ __forceinline__ float bits_to_normal_(uint32_t bits) {
  uint32_t m = (bits >> 9) | 0x3f800000u;
  float f = __uint_as_float(m) - 1.0f;
  float u = f * 2.0f + (-0.99999994f);
  u = fmaxf(-0.99999994f, u);
  return 1.41421356f * erfinv_f_(u);
}

// planar flows for one batch column (per-lane), returns logdet; zv updated in place
__device__ __forceinline__ float flows_dev(float zv[Z], const float* __restrict__ pu,
                                           const float* __restrict__ pw,
                                           const float* __restrict__ pb) {
  float ld = 0.0f;
  for (int f = 0; f < NF; ++f) {
    const float* w = pw + f * Z;
    const float* u = pu + f * Z;
    float wn2 = 0.0f, wu = 0.0f;
    #pragma unroll
    for (int i = 0; i < Z; ++i) { wn2 = fmaf(w[i], w[i], wn2); wu = fmaf(w[i], u[i], wu); }
    float coef = (softplusf_(wu) - 1.0f - wu) / wn2;
    float a_in = pb[f];
    #pragma unroll
    for (int i = 0; i < Z; ++i) a_in = fmaf(zv[i], w[i], a_in);
    float a = tanhf(a_in);
    float uw = 0.0f;
    #pragma unroll
    for (int i = 0; i < Z; ++i) {
      float uh = fmaf(coef, w[i], u[i]);
      uw = fmaf(uh, w[i], uw);
      zv[i] = fmaf(uh, a, zv[i]);
    }
    ld += logf(fabsf(1.0f + (1.0f - a * a) * uw) + 1e-12f);
  }
  return ld;
}

// ---------------- small utility kernels ----------------

__global__ __launch_bounds__(256) void k_transpose_x(const float* __restrict__ x,
                                                     float* __restrict__ xT) {
  int idx = blockIdx.x * blockDim.x + threadIdx.x;  // over B*L*F
  int f = idx % F;
  int t = (idx / F) % L;
  int b = idx / (F * L);
  xT[(t * F + f) * B + b] = x[idx];
}

__global__ __launch_bounds__(256) void k_noise(float* __restrict__ eps_z,
                                               float* __restrict__ kld_acc,
                                               uint32_t kz0, uint32_t kz1,
                                               uint32_t kp0, uint32_t kp1) {
  int i = blockIdx.x * blockDim.x + threadIdx.x;  // [0, HALF)
  uint32_t a0, a1, b0, b1;
  threefry2x32_(kz0, kz1, (uint32_t)i, (uint32_t)(i + HALF), a0, a1);
  float ez0 = bits_to_normal_(a0);
  float ez1 = bits_to_normal_(a1);
  eps_z[i] = ez0;
  eps_z[i + HALF] = ez1;
  threefry2x32_(kp0, kp1, (uint32_t)i, (uint32_t)(i + HALF), b0, b1);
  float ep0 = bits_to_normal_(b0);
  float ep1 = bits_to_normal_(b1);
  float local = -0.5f * (ez0 * ez0 + ez1 * ez1) + 0.5f * (ep0 * ep0 + ep1 * ep1);
  waveReduceAtomicAdd(kld_acc, local, threadIdx.x);
}

__global__ void k_finalize(const float* __restrict__ acc, float* __restrict__ out) {
  out[(size_t)B * L * F] = acc[1];      // recon
  out[(size_t)B * L * F + 1] = acc[0];  // kld
}

// ---------------- weight composition (once per launch) ----------------
__global__ __launch_bounds__(256) void k_compose(
    const float* __restrict__ A, const float* __restrict__ bA,
    const float* __restrict__ W2, const float* __restrict__ b2,
    float* __restrict__ Wc, float* __restrict__ bc) {
  const int r = blockIdx.x;
  const int k = threadIdx.x;
  float acc0 = 0.f, acc1 = 0.f;
  for (int j = 0; j < D; ++j) {
    float a = A[(size_t)r * D + j];          // wave-uniform
    acc0 = fmaf(a, W2[(size_t)j * D + k], acc0);
    acc1 = fmaf(a, W2[(size_t)j * D + k + 256], acc1);
  }
  Wc[(size_t)r * D + k] = acc0;
  Wc[(size_t)r * D + k + 256] = acc1;
  float accb = 0.f;
  for (int j = k; j < D; j += 256) accb += A[(size_t)r * D + j] * b2[j];
  __shared__ float s[256];
  s[k] = accb;
  __syncthreads();
  for (int off = 128; off > 0; off >>= 1) {
    if (k < off) s[k] += s[k + off];
    __syncthreads();
  }
  if (k == 0) bc[r] = s[0] + bA[r];
}

// ---------------- GRU phase (device) ----------------
// blk2 in [0,256): row-block rb=blk2>>2 (8 rows), batch group bg=blk2&3.
// THETA: wave0 runs planar flows (z-input, coherent loads); j0==0 publishes
// -logdet. Hidden-state reads/writes are agent-coherent (cross-XCD).
template<bool THETA>
__device__ __forceinline__ void gru_phase(
    int blk2, const float* __restrict__ xin, const float* __restrict__ hT,
    const float* __restrict__ Wih, const float* __restrict__ Whh,
    const float* __restrict__ bih, const float* __restrict__ bhh,
    float* __restrict__ hout,
    const float* pu, const float* pw, const float* pb, float* kld_acc,
    int w0h, float (&red)[4][4][8][64]) {
  const int tid = threadIdx.x;
  const int lane = tid & 63;
  const int wv = __builtin_amdgcn_readfirstlane(tid >> 6);
  const int j0 = (blk2 >> 2) * 8;
  const int b0 = (blk2 & 3) * 64;
  const int b = b0 + lane;
  constexpr int K1 = THETA ? Z : F;

  float accR[8], accZ[8], accNX[8], accNH[8];
  #pragma unroll
  for (int r = 0; r < 8; ++r) { accR[r] = 0.f; accZ[r] = 0.f; accNX[r] = 0.f; accNH[r] = 0.f; }

  float zv[Z];
  float ld = 0.0f;

  if (wv == 0) {
    const float* wr = Wih + (size_t)(0 * H + j0) * K1;
    const float* wz = Wih + (size_t)(1 * H + j0) * K1;
    const float* wn = Wih + (size_t)(2 * H + j0) * K1;
    if (THETA) {
      #pragma unroll
      for (int i = 0; i < Z; ++i) zv[i] = aload_(xin + i * B + b);
      ld = flows_dev(zv, pu, pw, pb);
      #pragma unroll
      for (int k = 0; k < Z; k += 4) {
        #pragma unroll
        for (int r = 0; r < 8; ++r) {
          const float4 w0 = *(const float4*)(wr + r * K1 + k);
          const float4 w1 = *(const float4*)(wz + r * K1 + k);
          const float4 w2 = *(const float4*)(wn + r * K1 + k);
          accR[r]  = fmaf(w0.x, zv[k], fmaf(w0.y, zv[k+1], fmaf(w0.z, zv[k+2], fmaf(w0.w, zv[k+3], accR[r]))));
          accZ[r]  = fmaf(w1.x, zv[k], fmaf(w1.y, zv[k+1], fmaf(w1.z, zv[k+2], fmaf(w1.w, zv[k+3], accZ[r]))));
          accNX[r] = fmaf(w2.x, zv[k], fmaf(w2.y, zv[k+1], fmaf(w2.z, zv[k+2], fmaf(w2.w, zv[k+3], accNX[r]))));
        }
      }
    } else {
      for (int k = 0; k < K1; ++k) {
        float a = xin[k * B + b];
        #pragma unroll
        for (int r = 0; r < 8; ++r) {
          accR[r]  = fmaf(wr[r * K1 + k], a, accR[r]);
          accZ[r]  = fmaf(wz[r * K1 + k], a, accZ[r]);
          accNX[r] = fmaf(wn[r * K1 + k], a, accNX[r]);
        }
      }
    }
  }

  // h-part (all bounds multiples of 4); hT loads are coherent
  const int rest = (H - w0h) / 3;
  const int hlo = (wv == 0) ? 0 : w0h + (wv - 1) * rest;
  const int hhi = (wv == 0) ? w0h : hlo + rest;
  {
    const float* vr = Whh + (size_t)(0 * H + j0) * H;
    const float* vz = Whh + (size_t)(1 * H + j0) * H;
    const float* vn = Whh + (size_t)(2 * H + j0) * H;
    #pragma unroll 2
    for (int k = hlo; k < hhi; k += 4) {
      const float a0 = aload_(hT + (size_t)(k + 0) * B + b);
      const float a1 = aload_(hT + (size_t)(k + 1) * B + b);
      const float a2 = aload_(hT + (size_t)(k + 2) * B + b);
      const float a3 = aload_(hT + (size_t)(k + 3) * B + b);
      #pragma unroll
      for (int r = 0; r < 8; ++r) {
        const float4 w0 = *(const float4*)(vr + (size_t)r * H + k);
        const float4 w1 = *(const float4*)(vz + (size_t)r * H + k);
        const float4 w2 = *(const float4*)(vn + (size_t)r * H + k);
        accR[r]  = fmaf(w0.x, a0, fmaf(w0.y, a1, fmaf(w0.z, a2, fmaf(w0.w, a3, accR[r]))));
        accZ[r]  = fmaf(w1.x, a0, fmaf(w1.y, a1, fmaf(w1.z, a2, fmaf(w1.w, a3, accZ[r]))));
        accNH[r] = fmaf(w2.x, a0, fmaf(w2.y, a1, fmaf(w2.z, a2, fmaf(w2.w, a3, accNH[r]))));
      }
    }
  }

  #pragma unroll
  for (int r = 0; r < 8; ++r) {
    red[wv][0][r][lane] = accR[r];
    red[wv][1][r][lane] = accZ[r];
    red[wv][2][r][lane] = accNX[r];
    red[wv][3][r][lane] = accNH[r];
  }

  if (THETA) {
    if (wv == 0 && j0 == 0) {
      waveReduceAtomicAdd(kld_acc, -ld, lane);
    }
  }

  __syncthreads();

  #pragma unroll
  for (int it = tid; it < 512; it += 256) {
    const int r = it >> 6, l = it & 63;
    float sR = 0.f, sZ = 0.f, sNX = 0.f, sNH = 0.f;
    #pragma unroll
    for (int w = 0; w < 4; ++w) {
      sR  += red[w][0][r][l];
      sZ  += red[w][1][r][l];
      sNX += red[w][2][r][l];
      sNH += red[w][3][r][l];
    }
    const int j = j0 + r;
    const int bb = b0 + l;
    const float rg = sigmoidf_(sR + bih[j] + bhh[j]);
    const float zg = sigmoidf_(sZ + bih[H + j] + bhh[H + j]);
    const float ng = tanhf(sNX + bih[2 * H + j] + rg * (sNH + bhh[2 * H + j]));
    const float hp = aload_(hT + (size_t)j * B + bb);
    astore_(hout + (size_t)j * B + bb, (1.0f - zg) * ng + zg * hp);
  }
}

// ---------------- linear phase (device): 8 rows/block, K split 4 ways -------
__device__ __forceinline__ void lin8_phase(
    int blk2, const float* __restrict__ A1, int K1v,
    const float* __restrict__ W, const float* __restrict__ bias,
    float* __restrict__ outp, int relu, float* shbase) {
  const int tid = threadIdx.x;
  const int lane = tid & 63;
  const int wv = __builtin_amdgcn_readfirstlane(tid >> 6);
  const int r0 = (blk2 >> 2) * 8;
  const int b0 = (blk2 & 3) * 64;
  const int b = b0 + lane;
  const int Kv = K1v;
  const int klo = wv * (Kv >> 2);
  const int khi = klo + (Kv >> 2);

  float acc[8];
  #pragma unroll
  for (int r = 0; r < 8; ++r) acc[r] = 0.f;

  const float* wbase = W + (size_t)r0 * Kv;
  #pragma unroll 4
  for (int k = klo; k < khi; k += 4) {
    const float a0 = aload_(A1 + (size_t)(k + 0) * B + b);
    const float a1 = aload_(A1 + (size_t)(k + 1) * B + b);
    const float a2 = aload_(A1 + (size_t)(k + 2) * B + b);
    const float a3 = aload_(A1 + (size_t)(k + 3) * B + b);
    #pragma unroll
    for (int r = 0; r < 8; ++r) {
      const float4 w4 = *(const float4*)(wbase + (size_t)r * Kv + k);
      acc[r] = fmaf(w4.x, a0, fmaf(w4.y, a1, fmaf(w4.z, a2, fmaf(w4.w, a3, acc[r]))));
    }
  }

  float* red = shbase;  // [4][8][64]
  #pragma unroll
  for (int r = 0; r < 8; ++r) red[(wv * 8 + r) * 64 + lane] = acc[r];
  __syncthreads();

  #pragma unroll
  for (int it = tid; it < 512; it += 256) {
    int r = it >> 6, l = it & 63;
    float s = red[(0 * 8 + r) * 64 + l] + red[(1 * 8 + r) * 64 + l]
            + red[(2 * 8 + r) * 64 + l] + red[(3 * 8 + r) * 64 + l] + bias[r0 + r];
    if (relu) s = fmaxf(s, 0.f);
    astore_(outp + (size_t)(r0 + r) * B + b0 + l, s);
  }
}

// ---------------- phi MLP1 phase with in-register flows -------------------
// Waves 0-2: 140 h-rows each; wave3: 92 h-rows + flows(z0_prev) + 16 z-rows.
__device__ __forceinline__ void mlp1_phi_phase(
    int blk2, const float* __restrict__ hphiT, const float* __restrict__ z0prev,
    const float* __restrict__ W, const float* __restrict__ bias,
    float* __restrict__ h1T,
    const float* pu, const float* pw, const float* pb, float* shbase) {
  const int tid = threadIdx.x;
  const int lane = tid & 63;
  const int wv = __builtin_amdgcn_readfirstlane(tid >> 6);
  const int r0 = (blk2 >> 2) * 8;
  const int b0 = (blk2 & 3) * 64;
  const int b = b0 + lane;
  constexpr int Kv = H + Z;  // 528
  const int klo = wv * 140;
  const int khi = (wv == 3) ? H : klo + 140;

  float acc[8];
  #pragma unroll
  for (int r = 0; r < 8; ++r) acc[r] = 0.f;

  const float* wbase = W + (size_t)r0 * Kv;
  #pragma unroll 4
  for (int k = klo; k < khi; k += 4) {
    const float a0 = aload_(hphiT + (size_t)(k + 0) * B + b);
    const float a1 = aload_(hphiT + (size_t)(k + 1) * B + b);
    const float a2 = aload_(hphiT + (size_t)(k + 2) * B + b);
    const float a3 = aload_(hphiT + (size_t)(k + 3) * B + b);
    #pragma unroll
    for (int r = 0; r < 8; ++r) {
      const float4 w4 = *(const float4*)(wbase + (size_t)r * Kv + k);
      acc[r] = fmaf(w4.x, a0, fmaf(w4.y, a1, fmaf(w4.z, a2, fmaf(w4.w, a3, acc[r]))));
    }
  }
  if (wv == 3 && z0prev != nullptr) {   // i==0: z_prev == 0 -> zero contribution
    float zv[Z];
    #pragma unroll
    for (int i = 0; i < Z; ++i) zv[i] = aload_(z0prev + i * B + b);
    flows_dev(zv, pu, pw, pb);
    #pragma unroll
    for (int i = 0; i < Z; i += 4) {
      #pragma unroll
      for (int r = 0; r < 8; ++r) {
        const float4 w4 = *(const float4*)(wbase + (size_t)r * Kv + H + i);
        acc[r] = fmaf(w4.x, zv[i], fmaf(w4.y, zv[i+1], fmaf(w4.z, zv[i+2], fmaf(w4.w, zv[i+3], acc[r]))));
      }
    }
  }

  float* red = shbase;  // [4][8][64]
  #pragma unroll
  for (int r = 0; r < 8; ++r) red[(wv * 8 + r) * 64 + lane] = acc[r];
  __syncthreads();

  #pragma unroll
  for (int it = tid; it < 512; it += 256) {
    int r = it >> 6, l = it & 63;
    float s = red[(0 * 8 + r) * 64 + l] + red[(1 * 8 + r) * 64 + l]
            + red[(2 * 8 + r) * 64 + l] + red[(3 * 8 + r) * 64 + l] + bias[r0 + r];
    s = fmaxf(s, 0.f);
    astore_(h1T + (size_t)(r0 + r) * B + b0 + l, s);
  }
}

// ---------------- z head phase (device): blk2 in [0,16) -------------------
__device__ __forceinline__ void zhead_phase(
    int blk2, const float* __restrict__ h1T,
    const float* __restrict__ Wzl, const float* __restrict__ bzl,
    const float* __restrict__ Wzs, const float* __restrict__ bzs,
    const float* __restrict__ eps_t, float* __restrict__ z0T,
    float* kld_acc, float* shbase) {
  const int tid = threadIdx.x;
  const int lane = tid & 63;
  const int wv = __builtin_amdgcn_readfirstlane(tid >> 6);
  const int z0q = (blk2 >> 2) * 4;
  const int b0 = (blk2 & 3) * 64;
  const int b = b0 + lane;
  const int klo = wv * (D >> 2), khi = klo + (D >> 2);

  const float* wp[8];
  #pragma unroll
  for (int i = 0; i < 8; ++i) {
    int zz = z0q + (i >> 1);
    wp[i] = ((i & 1) ? Wzs : Wzl) + (size_t)zz * D;
  }
  float acc[8];
  #pragma unroll
  for (int i = 0; i < 8; ++i) acc[i] = 0.f;
  #pragma unroll 4
  for (int k = klo; k < khi; k += 4) {
    const float a0 = aload_(h1T + (size_t)(k + 0) * B + b);
    const float a1 = aload_(h1T + (size_t)(k + 1) * B + b);
    const float a2 = aload_(h1T + (size_t)(k + 2) * B + b);
    const float a3 = aload_(h1T + (size_t)(k + 3) * B + b);
    #pragma unroll
    for (int i = 0; i < 8; ++i) {
      const float4 w4 = *(const float4*)(wp[i] + k);
      acc[i] = fmaf(w4.x, a0, fmaf(w4.y, a1, fmaf(w4.z, a2, fmaf(w4.w, a3, acc[i]))));
    }
  }

  float* red = shbase;  // [4][8][64]
  #pragma unroll
  for (int i = 0; i < 8; ++i) red[(wv * 8 + i) * 64 + lane] = acc[i];
  __syncthreads();

  int zi = tid >> 6, l = tid & 63;
  int zz = z0q + zi;
  int bb = b0 + l;
  float sl = red[(0 * 8 + 2 * zi) * 64 + l] + red[(1 * 8 + 2 * zi) * 64 + l]
           + red[(2 * 8 + 2 * zi) * 64 + l] + red[(3 * 8 + 2 * zi) * 64 + l] + bzl[zz];
  float ss = red[(0 * 8 + 2 * zi + 1) * 64 + l] + red[(1 * 8 + 2 * zi + 1) * 64 + l]
           + red[(2 * 8 + 2 * zi + 1) * 64 + l] + red[(3 * 8 + 2 * zi + 1) * 64 + l] + bzs[zz];
  float scale = softplusf_(ss) + 1e-6f;
  float ez = eps_t[bb * Z + zz];
  astore_(z0T + zz * B + bb, sl + scale * ez);
  waveReduceAtomicAdd(kld_acc, -logf(scale), tid);
}

// ---------------- y head phase (device): blk2 in [0,40) -------------------
__device__ __forceinline__ void yhead_phase(
    int blk2, int t, const float* __restrict__ g1T,
    const float* __restrict__ Wyl, const float* __restrict__ byl,
    const float* __restrict__ Wys, const float* __restrict__ bys,
    const float* __restrict__ xT, float* __restrict__ out_yloc,
    float* recon_acc, float* shbase) {
  const int tid = threadIdx.x;
  const int lane = tid & 63;
  const int wv = __builtin_amdgcn_readfirstlane(tid >> 6);
  const int f0 = (blk2 >> 2) * 4;
  const int b0 = (blk2 & 3) * 64;
  const int b = b0 + lane;
  const int klo = wv * (D >> 2), khi = klo + (D >> 2);

  const float* wp[8];
  #pragma unroll
  for (int i = 0; i < 8; ++i) {
    int ff = f0 + (i >> 1);
    int fc = ff < F ? ff : 0;
    wp[i] = ((i & 1) ? Wys : Wyl) + (size_t)fc * D;
  }
  float acc[8];
  #pragma unroll
  for (int i = 0; i < 8; ++i) acc[i] = 0.f;
  #pragma unroll 4
  for (int k = klo; k < khi; k += 4) {
    const float a0 = aload_(g1T + (size_t)(k + 0) * B + b);
    const float a1 = aload_(g1T + (size_t)(k + 1) * B + b);
    const float a2 = aload_(g1T + (size_t)(k + 2) * B + b);
    const float a3 = aload_(g1T + (size_t)(k + 3) * B + b);
    #pragma unroll
    for (int i = 0; i < 8; ++i) {
      const float4 w4 = *(const float4*)(wp[i] + k);
      acc[i] = fmaf(w4.x, a0, fmaf(w4.y, a1, fmaf(w4.z, a2, fmaf(w4.w, a3, acc[i]))));
    }
  }

  float* red = shbase;  // [4][8][64]
  #pragma unroll
  for (int i = 0; i < 8; ++i) red[(wv * 8 + i) * 64 + lane] = acc[i];
  __syncthreads();

  int fi = tid >> 6, l = tid & 63;
  int ff = f0 + fi;
  int bb = b0 + l;
  float nl = 0.0f;
  if (ff < F) {
    float loc = red[(0 * 8 + 2 * fi) * 64 + l] + red[(1 * 8 + 2 * fi) * 64 + l]
              + red[(2 * 8 + 2 * fi) * 64 + l] + red[(3 * 8 + 2 * fi) * 64 + l] + byl[ff];
    float sp = red[(0 * 8 + 2 * fi + 1) * 64 + l] + red[(1 * 8 + 2 * fi + 1) * 64 + l]
             + red[(2 * 8 + 2 * fi + 1) * 64 + l] + red[(3 * 8 + 2 * fi + 1) * 64 + l] + bys[ff];
    float scale = softplusf_(sp) + 1e-6f;
    out_yloc[((size_t)bb * L + t) * F + ff] = loc;
    float xv = xT[((size_t)t * F + ff) * B + bb];
    float d = (xv - loc) / scale;
    nl = 0.5f * d * d + logf(scale) + 0.5f * LOG2PI_F;
  }
  waveReduceAtomicAdd(recon_acc, nl, tid);
}

// ---------------- persistent kernel ----------------
struct PP {
  const float *xT, *eps_z;
  const float *phi_Wih, *phi_Whh, *phi_bih, *phi_bhh, *phi_W1, *phi_b1;
  const float *th_Wih, *th_Whh, *th_bih, *th_bhh, *th_W1, *th_b1;
  const float *Wzl, *bzl, *Wzs, *bzs, *Wyl, *byl, *Wys, *bys;
  const float *pu, *pw, *pb;
  float *phi0, *phi1, *th0, *th1, *z0a, *z0b, *h1T, *g1T, *acc, *out;
  uint32_t* bar;
};

// Schedule (R4), 2 grid barriers per iteration:
//   A(i): phiGRU(i)[blk 0..255, heads piggyback on 0..55] | thGRU(i-2)[256..511]
//   B(i): phiMLP1(i)+reg-flows [0..255] | thMLP1(i-2) [256..511]
__global__ __launch_bounds__(256, 2) void k_persist(PP P) {
  __shared__ float red[4][4][8][64];  // 32 KB; flat-reused by heads/MLP
  float* sh = &red[0][0][0][0];
  const int blk = blockIdx.x;
  uint32_t n = 0;

  for (int i = 0; i <= L + 2; ++i) {
    const bool hasPhi = (i < L);
    const bool hasTh  = (i >= 2 && i <= L + 1);
    const bool hasZ   = (i >= 1 && i <= L);
    const bool hasY   = (i >= 3);

    const float* xt     = P.xT + (size_t)(hasPhi ? i : 0) * F * B;
    const float* phi_c  = (i & 1) ? P.phi1 : P.phi0;   // phi_h(i-1)
    float*       phi_n  = (i & 1) ? P.phi0 : P.phi1;   // phi_h(i)
    const float* z0_in  = (i & 1) ? P.z0b : P.z0a;     // z0(i-2)
    const float* th_c   = (i & 1) ? P.th0 : P.th1;     // th_h(i-3)
    float*       th_n   = (i & 1) ? P.th1 : P.th0;     // th_h(i-2)
    float*       z0_out = (i & 1) ? P.z0a : P.z0b;     // z0(i-1)

    // ---- phase A ----
    if (blk < 256) {
      if (hasPhi)
        gru_phase<false>(blk, xt, phi_c, P.phi_Wih, P.phi_Whh, P.phi_bih,
                         P.phi_bhh, phi_n, nullptr, nullptr, nullptr, nullptr,
                         104, red);
      if (blk < 56) {
        __syncthreads();  // protect red reuse between GRU epilogue and head
        if (blk < 16) {
          if (hasZ)
            zhead_phase(blk, P.h1T, P.Wzl, P.bzl, P.Wzs, P.bzs,
                        P.eps_z + (size_t)(i - 1) * B * Z, z0_out, P.acc, sh);
        } else {
          if (hasY)
            yhead_phase(blk - 16, i - 3, P.g1T, P.Wyl, P.byl, P.Wys, P.bys,
                        P.xT, P.out, P.acc + 1, sh);
        }
      }
    } else {
      if (hasTh)
        gru_phase<true>(blk - 256, z0_in, th_c, P.th_Wih, P.th_Whh, P.th_bih,
                        P.th_bhh, th_n, P.pu, P.pw, P.pb, P.acc, 56, red);
    }
    ++n; gsync_(P.bar, blk, n);

    // ---- phase B ----
    if (blk < 256) {
      if (hasPhi)
        mlp1_phi_phase(blk, phi_n, (i >= 1) ? z0_out : nullptr,
                       P.phi_W1, P.phi_b1, P.h1T, P.pu, P.pw, P.pb, sh);
    } else {
      if (hasTh)
        lin8_phase(blk - 256, th_n, H, P.th_W1, P.th_b1, P.g1T, 1, sh);
    }
    ++n; gsync_(P.bar, blk, n);
  }
}

}  // namespace

extern "C" void kernel_launch(void* const* d_in, const int* in_sizes, int n_in,
                              void* d_out, int out_size, void* d_ws, size_t ws_size,
                              hipStream_t stream) {
  const float* x        = (const float*)d_in[0];
  const float* phi_Wih  = (const float*)d_in[1];
  const float* phi_Whh  = (const float*)d_in[2];
  const float* phi_bih  = (const float*)d_in[3];
  const float* phi_bhh  = (const float*)d_in[4];
  const float* phi_W1   = (const float*)d_in[5];
  const float* phi_b1   = (const float*)d_in[6];
  const float* phi_W2   = (const float*)d_in[7];
  const float* phi_b2   = (const float*)d_in[8];
  const float* zloc_W   = (const float*)d_in[9];
  const float* zloc_b   = (const float*)d_in[10];
  const float* zscale_W = (const float*)d_in[11];
  const float* zscale_b = (const float*)d_in[12];
  const float* pu       = (const float*)d_in[13];
  const float* pw       = (const float*)d_in[14];
  const float* pb       = (const float*)d_in[15];
  const float* th_Wih   = (const float*)d_in[16];
  const float* th_Whh   = (const float*)d_in[17];
  const float* th_bih   = (const float*)d_in[18];
  const float* th_bhh   = (const float*)d_in[19];
  const float* th_W1    = (const float*)d_in[20];
  const float* th_b1    = (const float*)d_in[21];
  const float* th_W2    = (const float*)d_in[22];
  const float* th_b2    = (const float*)d_in[23];
  const float* xloc_W   = (const float*)d_in[24];
  const float* xloc_b   = (const float*)d_in[25];
  const float* xscale_W = (const float*)d_in[26];
  const float* xscale_b = (const float*)d_in[27];

  float* out = (float*)d_out;
  float* ws = (float*)d_ws;

  // workspace layout (floats)
  float* acc   = ws;                        // [0]=kld, [1]=recon
  uint32_t* bar = (uint32_t*)(ws + 64);     // 2048 dwords, cacheline-spread
  float* eps_z = ws + 64 + 2048;            // LBZ
  float* xT    = eps_z + LBZ;               // LFB
  float* phi0  = xT + LFB;                  // HB
  float* phi1  = phi0 + HB;                 // HB
  float* th0   = phi1 + HB;                 // HB
  float* th1   = th0 + HB;                  // HB
  float* z0a   = th1 + HB;                  // ZB
  float* z0b   = z0a + ZB;                  // ZB
  float* h1T   = z0b + ZB;                  // DB
  float* g1T   = h1T + DB;                  // DB
  float* Wzl   = g1T + DB;                  // Z*D
  float* Wzs   = Wzl + Z * D;               // Z*D
  float* bzl   = Wzs + Z * D;               // 64
  float* bzs   = bzl + 64;                  // 64
  float* Wyl   = bzs + 64;                  // F*D
  float* Wys   = Wyl + F * D;               // F*D
  float* byl   = Wys + F * D;               // 64
  float* bys   = byl + 64;                  // 64

  hipMemsetAsync(ws, 0, (64 + 2048) * sizeof(float), stream);   // acc + barrier
  hipMemsetAsync(phi0, 0, (size_t)HB * sizeof(float), stream);  // phi_h(-1)
  hipMemsetAsync(th1, 0, (size_t)HB * sizeof(float), stream);   // th_h(-1)

  // JAX PRNG: key(42)=(0,42); split -> kz, kp
  uint32_t a0, a1, b0, b1;
  threefry2x32_(0u, 42u, 0u, 2u, a0, a1);
  threefry2x32_(0u, 42u, 1u, 3u, b0, b1);
  const uint32_t kz0 = a0, kz1 = b0, kp0 = a1, kp1 = b1;

  k_transpose_x<<<(B * L * F) / 256, 256, 0, stream>>>(x, xT);
  k_noise<<<HALF / 256, 256, 0, stream>>>(eps_z, acc, kz0, kz1, kp0, kp1);

  // Compose linear MLP2 into the z/y heads: Wc = headW @ W2, bc = headW @ b2 + headb.
  k_compose<<<Z, 256, 0, stream>>>(zloc_W, zloc_b, phi_W2, phi_b2, Wzl, bzl);
  k_compose<<<Z, 256, 0, stream>>>(zscale_W, zscale_b, phi_W2, phi_b2, Wzs, bzs);
  k_compose<<<F, 256, 0, stream>>>(xloc_W, xloc_b, th_W2, th_b2, Wyl, byl);
  k_compose<<<F, 256, 0, stream>>>(xscale_W, xscale_b, th_W2, th_b2, Wys, bys);

  PP P;
  P.xT = xT; P.eps_z = eps_z;
  P.phi_Wih = phi_Wih; P.phi_Whh = phi_Whh; P.phi_bih = phi_bih; P.phi_bhh = phi_bhh;
  P.phi_W1 = phi_W1; P.phi_b1 = phi_b1;
  P.th_Wih = th_Wih; P.th_Whh = th_Whh; P.th_bih = th_bih; P.th_bhh = th_bhh;
  P.th_W1 = th_W1; P.th_b1 = th_b1;
  P.Wzl = Wzl; P.bzl = bzl; P.Wzs = Wzs; P.bzs = bzs;
  P.Wyl = Wyl; P.byl = byl; P.Wys = Wys; P.bys = bys;
  P.pu = pu; P.pw = pw; P.pb = pb;
  P.phi0 = phi0; P.phi1 = phi1; P.th0 = th0; P.th1 = th1;
  P.z0a = z0a; P.z0b = z0b; P.h1T = h1T; P.g1T = g1T;
  P.acc = acc; P.out = out; P.bar = bar;

  k_persist<<<GRIDN, 256, 0, stream>>>(P);

  k_finalize<<<1, 1, 0, stream>>>(acc, out);
}